// Round 10
// baseline (19.528 us; speedup 1.0000x reference)
//
#include <hip/hip_runtime.h>
#include <math.h>

#define BATCH 16
#define SEQ 1024
#define MH 4
#define DIM 64
#define NCHUNK 8
#define CHUNK 128
#define WS_STRIDE 68   // per-tile: [0]=M, [1]=S, [2..65]=A[64], pad to 68

// ---------------- K1: per-(b,m,chunk) flash partials, no redundancy ----------------
// 512 blocks x 256 threads (4 waves). Wave w owns 32 positions; lane d owns dim d.
__global__ __launch_bounds__(256)
void teedam_partials(const float* __restrict__ values,
                     const float* __restrict__ pre,
                     float* __restrict__ ws) {
    const int blk = blockIdx.x;          // = bm*8 + c
    const int c   = blk & (NCHUNK - 1);
    const int bm  = blk >> 3;
    const int m   = bm & (MH - 1);
    const int b   = bm >> 2;

    const int tid  = threadIdx.x;
    const int w    = tid >> 6;           // 0..3
    const int lane = tid & 63;

    const int bP = b * SEQ;
    const int q0 = c * CHUNK + w * 32;

    __shared__ float sM[4], sS[4], sA[4][DIM];

    // wave's 32 pre values in lanes 0..31
    float pre_l = (lane < 32) ? pre[(size_t)(bP + q0 + lane) * MH + m] : -INFINITY;

    // wave-local max over 32 positions (group 0 holds data)
    float mx = pre_l;
    #pragma unroll
    for (int off = 16; off > 0; off >>= 1)
        mx = fmaxf(mx, __shfl_xor(mx, off, 64));
    if (lane == 0) sM[w] = mx;
    __syncthreads();
    const float Mc = fmaxf(fmaxf(sM[0], sM[1]), fmaxf(sM[2], sM[3]));

    // exp-weighted sums over the wave's 32 positions
    const float* vb = values + (size_t)(bP + q0) * DIM + lane;
    float S = 0.f, A = 0.f;
    #pragma unroll
    for (int i = 0; i < 32; ++i) {
        float wq = __expf(__shfl(pre_l, i, 64) - Mc);
        S += wq;
        A = fmaf(wq, vb[(size_t)i * DIM], A);
    }
    if (lane == 0) sS[w] = S;
    sA[w][lane] = A;
    __syncthreads();

    if (w == 0) {
        float St = sS[0] + sS[1] + sS[2] + sS[3];
        float At = sA[0][lane] + sA[1][lane] + sA[2][lane] + sA[3][lane];
        float* wp = ws + (size_t)blk * WS_STRIDE;
        if (lane == 0) { wp[0] = Mc; wp[1] = St; }
        wp[2 + lane] = At;
    }
}

// ---------------- K2: combine prefix partials + local scan + write ----------------
// 512 blocks x 512 threads (8 waves). Wave w owns 16 positions; lane d owns dim d.
__global__ __launch_bounds__(512)
void teedam_finalize(const float* __restrict__ values,
                     const float* __restrict__ pre,
                     const float* __restrict__ mask,
                     const float* __restrict__ ws,
                     float* __restrict__ out) {
    const int blk = blockIdx.x;
    const int c   = blk & (NCHUNK - 1);
    const int bm  = blk >> 3;
    const int m   = bm & (MH - 1);
    const int b   = bm >> 2;

    const int tid  = threadIdx.x;
    const int w    = tid >> 6;           // 0..7
    const int lane = tid & 63;

    const int bP = b * SEQ;
    const int p0 = c * CHUNK;

    __shared__ float sS[8], sA[8][DIM];

    // G = max of chunk maxima j<=c (== cummax at end of this chunk: exact)
    const float* wsbase = ws + (size_t)(bm * NCHUNK) * WS_STRIDE;
    float G = -INFINITY;
    for (int j = 0; j <= c; ++j) G = fmaxf(G, wsbase[(size_t)j * WS_STRIDE]);

    // prefix sums from partials j<c, rescaled to G
    float Spre = 0.f, Apre = 0.f;
    for (int j = 0; j < c; ++j) {
        const float* wj = wsbase + (size_t)j * WS_STRIDE;
        float ej = __expf(wj[0] - G);
        Spre = fmaf(wj[1], ej, Spre);
        Apre = fmaf(wj[2 + lane], ej, Apre);
    }

    // local pass 1: wave's 16-position sums
    const int q0c = p0 + w * 16;
    float pre_c  = (lane < 16) ? pre[(size_t)(bP + q0c + lane) * MH + m] : 0.f;
    float mask_c = (lane < 16) ? mask[bP + q0c + lane] : 0.f;
    const float* vc = values + (size_t)(bP + q0c) * DIM + lane;

    float Sc = 0.f, Ac = 0.f;
    #pragma unroll
    for (int i = 0; i < 16; ++i) {
        float wq = __expf(__shfl(pre_c, i, 64) - G);
        Sc += wq;
        Ac = fmaf(wq, vc[(size_t)i * DIM], Ac);
    }
    if (lane == 0) sS[w] = Sc;
    sA[w][lane] = Ac;
    __syncthreads();

    // running state entering this wave's 16 positions
    float S = Spre, A = Apre;
    for (int j = 0; j < w; ++j) { S += sS[j]; A += sA[j][lane]; }

    // local pass 2: rescan + write
    float* op = out + ((size_t)(bP + q0c) * MH + m) * DIM + lane;
    #pragma unroll
    for (int i = 0; i < 16; ++i) {
        float wq = __expf(__shfl(pre_c, i, 64) - G);
        float vv = vc[(size_t)i * DIM];
        S += wq;
        A = fmaf(wq, vv, A);
        float mk = __shfl(mask_c, i, 64);
        op[(size_t)i * MH * DIM] = A * (mk * __builtin_amdgcn_rcpf(S));
    }
}

extern "C" void kernel_launch(void* const* d_in, const int* in_sizes, int n_in,
                              void* d_out, int out_size, void* d_ws, size_t ws_size,
                              hipStream_t stream) {
    const float* values = (const float*)d_in[0];
    const float* pre    = (const float*)d_in[1];
    const float* mask   = (const float*)d_in[2];
    float*       out    = (float*)d_out;
    float*       ws     = (float*)d_ws;

    dim3 grid(BATCH * MH * NCHUNK);      // 512 tiles
    hipLaunchKernelGGL(teedam_partials, grid, dim3(256), 0, stream,
                       values, pre, ws);
    hipLaunchKernelGGL(teedam_finalize, grid, dim3(512), 0, stream,
                       values, pre, mask, ws, out);
}

// Round 11
// 17.677 us; speedup vs baseline: 1.1047x; 1.1047x over previous
//
#include <hip/hip_runtime.h>
#include <math.h>

#define BATCH 16
#define SEQ 1024
#define MH 4
#define DIM 64
#define NCHUNK 8
#define CHUNK 128           // positions per block
#define WAVES 8
#define WSEG 16             // positions per wave in local scan
#define THREADS (WAVES * 64)

// Single-dispatch: one block per (b, m, chunk-of-128). Lane d owns dim d.
// Unnormalized-exp cumsum stable via per-chain bound G (= max over
// [0, chunk_end), exact algebra vs the reference's cummax). Prefix over
// earlier chunks computed redundantly in-block (R10 proved the redundancy
// is cheaper than a second dispatch). Phase C keeps wq / wq*v in registers
// so the output pass re-loads and re-computes nothing.
__global__ __launch_bounds__(THREADS)
void teedam_kernel(const float* __restrict__ values,
                   const float* __restrict__ pre,
                   const float* __restrict__ mask,
                   float* __restrict__ out) {
    const int blk  = blockIdx.x;
    const int c    = blk & (NCHUNK - 1);
    const int bm   = blk >> 3;
    const int m    = bm & (MH - 1);
    const int b    = bm >> 2;

    const int tid  = threadIdx.x;
    const int w    = tid >> 6;
    const int lane = tid & 63;

    const int bP = b * SEQ;
    const int p0 = c * CHUNK;

    __shared__ float lds_red[WAVES];
    __shared__ float lds_Sb[WAVES];
    __shared__ float lds_Sc[WAVES];
    __shared__ float lds_Ab[WAVES][DIM];
    __shared__ float lds_Ac[WAVES][DIM];

    // ---- phase A: G = max(pre) over [0, p0+CHUNK) for this (b,m) chain ----
    const int npos = p0 + CHUNK;
    float gmax = -INFINITY;
    for (int p = tid; p < npos; p += THREADS)
        gmax = fmaxf(gmax, pre[(size_t)(bP + p) * MH + m]);
    #pragma unroll
    for (int off = 32; off > 0; off >>= 1)
        gmax = fmaxf(gmax, __shfl_xor(gmax, off, 64));
    if (lane == 0) lds_red[w] = gmax;
    __syncthreads();
    float G = lds_red[0];
    #pragma unroll
    for (int j = 1; j < WAVES; ++j) G = fmaxf(G, lds_red[j]);

    // ---- phase B: partial sums over previous chunks [0, p0) ----
    float Sb0 = 0.f, Sb1 = 0.f, Ab0 = 0.f, Ab1 = 0.f;
    for (int t = 0; t < c; ++t) {
        const int g  = w + t * 8;
        const int q0 = g * 16;
        float pre_b = (lane < 16) ? pre[(size_t)(bP + q0 + lane) * MH + m] : 0.f;
        const float* vb = values + (size_t)(bP + q0) * DIM + lane;
        #pragma unroll
        for (int i = 0; i < 16; i += 2) {
            float w0 = __expf(__shfl(pre_b, i, 64) - G);
            float w1 = __expf(__shfl(pre_b, i + 1, 64) - G);
            Sb0 += w0;
            Sb1 += w1;
            Ab0 = fmaf(w0, vb[(size_t)i * DIM], Ab0);
            Ab1 = fmaf(w1, vb[(size_t)(i + 1) * DIM], Ab1);
        }
    }
    if (lane == 0) lds_Sb[w] = Sb0 + Sb1;
    lds_Ab[w][lane] = Ab0 + Ab1;

    // ---- phase C pass 1: wave's 16 positions; keep wq, wq*v in registers ----
    const int q0c = p0 + w * WSEG;
    float pre_c  = (lane < 16) ? pre[(size_t)(bP + q0c + lane) * MH + m] : 0.f;
    float mask_c = (lane < 16) ? mask[bP + q0c + lane] : 0.f;
    const float* vc = values + (size_t)(bP + q0c) * DIM + lane;

    float p_[WSEG], y_[WSEG];          // fully unrolled -> stays in VGPRs
    float Sc = 0.f, Ac = 0.f;
    #pragma unroll
    for (int i = 0; i < WSEG; ++i) {
        float wq = __expf(__shfl(pre_c, i, 64) - G);
        float vv = vc[(size_t)i * DIM];
        p_[i] = wq;
        y_[i] = wq * vv;
        Sc += wq;
        Ac += y_[i];
    }
    if (lane == 0) lds_Sc[w] = Sc;
    lds_Ac[w][lane] = Ac;
    __syncthreads();

    // ---- prefix entering this wave's segment ----
    float S = 0.f, A = 0.f;
    #pragma unroll
    for (int j = 0; j < WAVES; ++j) { S += lds_Sb[j]; A += lds_Ab[j][lane]; }
    for (int j = 0; j < w; ++j)     { S += lds_Sc[j]; A += lds_Ac[j][lane]; }

    // ---- phase C pass 2: accumulate from registers, write out ----
    float* op = out + ((size_t)(bP + q0c) * MH + m) * DIM + lane;
    #pragma unroll
    for (int i = 0; i < WSEG; ++i) {
        S += p_[i];
        A += y_[i];
        float mk = __shfl(mask_c, i, 64);
        op[(size_t)i * MH * DIM] = A * (mk * __builtin_amdgcn_rcpf(S));
    }
}

extern "C" void kernel_launch(void* const* d_in, const int* in_sizes, int n_in,
                              void* d_out, int out_size, void* d_ws, size_t ws_size,
                              hipStream_t stream) {
    const float* values = (const float*)d_in[0];
    const float* pre    = (const float*)d_in[1];
    const float* mask   = (const float*)d_in[2];
    float*       out    = (float*)d_out;

    dim3 grid(BATCH * MH * NCHUNK);   // 512 blocks
    dim3 block(THREADS);              // 512 threads = 8 waves
    hipLaunchKernelGGL(teedam_kernel, grid, block, 0, stream,
                       values, pre, mask, out);
}